// Round 13
// baseline (907.683 us; speedup 1.0000x reference)
//
#include <hip/hip_runtime.h>
#include <math.h>

#define N_NODES 100000
#define N_EDGES 1600000
#define DIM 48
#define NPB 16          // nodes per block (fused layer)
#define THREADS 192     // 16 nodes x 12 lanes
#define NODE_BLOCKS ((N_NODES + 255) / 256)   // 391
#define NXCD 8
#define XCD_RANGE (N_NODES / NXCD)            // 12500 exact
#define FILL_GRID 1024                        // multiple of 8
#define FILL_NGRP (FILL_GRID / NXCD)          // 128

// ============ CSR build (XCD-partitioned: each line written by one XCD) ============
__global__ __launch_bounds__(256) void hist_deg_xcd(
    const int* __restrict__ dst, int* __restrict__ deg)
{
    const int xcd = blockIdx.x & (NXCD - 1);      // heuristic: blockIdx%8 -> XCD
    const int grp = blockIdx.x >> 3;              // 0..FILL_NGRP-1
    const int lo = xcd * XCD_RANGE;
    const int hi = lo + XCD_RANGE;
    for (int e = grp * 256 + threadIdx.x; e < N_EDGES; e += FILL_NGRP * 256) {
        int d = dst[e];                            // coalesced
        if (d >= lo && d < hi) atomicAdd(&deg[d], 1);
    }
}

__global__ __launch_bounds__(256) void fill_csr_xcd(
    const int* __restrict__ src, const int* __restrict__ dst,
    int* __restrict__ cursor, int* __restrict__ csr_src)
{
    const int xcd = blockIdx.x & (NXCD - 1);
    const int grp = blockIdx.x >> 3;
    const int lo = xcd * XCD_RANGE;
    const int hi = lo + XCD_RANGE;
    for (int e = grp * 256 + threadIdx.x; e < N_EDGES; e += FILL_NGRP * 256) {
        int d = dst[e];                            // coalesced
        int s = src[e];                            // coalesced (load always)
        if (d >= lo && d < hi) {
            int pos = atomicAdd(&cursor[d], 1);
            csr_src[pos] = s;                      // pos within this XCD's csr range
        }
    }
}

__global__ __launch_bounds__(256) void block_sums(
    const int* __restrict__ deg, int* __restrict__ bsum)
{
    __shared__ int r[256];
    unsigned t = threadIdx.x;
    unsigned i = blockIdx.x * 256u + t;
    r[t] = (i < N_NODES) ? deg[i] : 0;
    __syncthreads();
    for (int s = 128; s > 0; s >>= 1) {
        if (t < (unsigned)s) r[t] += r[t + s];
        __syncthreads();
    }
    if (t == 0) bsum[blockIdx.x] = r[0];
}

// single block, 512 threads: exclusive scan of bsum[0..NODE_BLOCKS)
__global__ __launch_bounds__(512) void scan_block_sums(
    const int* __restrict__ bsum, int* __restrict__ bsum_ex)
{
    __shared__ int s[512];
    unsigned t = threadIdx.x;
    int v = (t < NODE_BLOCKS) ? bsum[t] : 0;
    s[t] = v;
    __syncthreads();
    for (int off = 1; off < 512; off <<= 1) {
        int u = (t >= (unsigned)off) ? s[t - off] : 0;
        __syncthreads();
        s[t] += u;
        __syncthreads();
    }
    bsum_ex[t] = s[t] - v;   // exclusive
}

__global__ __launch_bounds__(256) void write_offsets(
    const int* __restrict__ deg, const int* __restrict__ bsum_ex,
    int* __restrict__ row_off, int* __restrict__ cursor)
{
    __shared__ int s[256];
    unsigned t = threadIdx.x;
    unsigned i = blockIdx.x * 256u + t;
    int v = (i < N_NODES) ? deg[i] : 0;
    s[t] = v;
    __syncthreads();
    for (int off = 1; off < 256; off <<= 1) {
        int u = (t >= (unsigned)off) ? s[t - off] : 0;
        __syncthreads();
        s[t] += u;
        __syncthreads();
    }
    if (i < N_NODES) {
        int o = bsum_ex[blockIdx.x] + s[t] - v;  // exclusive prefix
        row_off[i] = o;
        cursor[i] = o;
    }
    if (i == 0) row_off[N_NODES] = N_EDGES;
}

// ============ fused layer: out = (CSR-gather-sum of h) @ Wr + br + h @ Wk ============
// 192 threads = 16 nodes x 12 lanes. Phase 1: gather to LDS. Phase 2: dense combine.
__global__ __launch_bounds__(THREADS) void fused_layer(
    const float* __restrict__ h, const int* __restrict__ row_off,
    const int* __restrict__ csr_src,
    const float* __restrict__ Wr, const float* __restrict__ br,
    const float* __restrict__ Wk, float* __restrict__ out)
{
    __shared__ float sWr[DIM * DIM];
    __shared__ float sWk[DIM * DIM];
    __shared__ float sbr[DIM];
    __shared__ float sAg[NPB][DIM];
    __shared__ float sH[NPB][DIM];

    // stage weights (once per block)
    for (int i = threadIdx.x; i < DIM * DIM; i += THREADS) {
        sWr[i] = Wr[i];
        sWk[i] = Wk[i];
    }
    if (threadIdx.x < DIM) sbr[threadIdx.x] = br[threadIdx.x];

    const unsigned ln = threadIdx.x / 12u;   // 0..15
    const unsigned q  = threadIdx.x % 12u;   // 0..11
    const unsigned node = blockIdx.x * NPB + ln;  // grid exact: 6250*16 = 100000

    // stage own h row
    const float4 hv = *reinterpret_cast<const float4*>(h + (size_t)node * DIM + q * 4);
    *reinterpret_cast<float4*>(&sH[ln][q * 4]) = hv;

    // CSR gather-sum, unrolled x4 for memory-level parallelism
    const int beg = row_off[node];
    const int end = row_off[node + 1];
    float4 a0 = make_float4(0.f, 0.f, 0.f, 0.f);
    float4 a1 = make_float4(0.f, 0.f, 0.f, 0.f);
    int i = beg;
    for (; i + 4 <= end; i += 4) {
        int s0 = csr_src[i + 0];
        int s1 = csr_src[i + 1];
        int s2 = csr_src[i + 2];
        int s3 = csr_src[i + 3];
        const float4 v0 = *reinterpret_cast<const float4*>(h + (size_t)s0 * DIM + q * 4);
        const float4 v1 = *reinterpret_cast<const float4*>(h + (size_t)s1 * DIM + q * 4);
        const float4 v2 = *reinterpret_cast<const float4*>(h + (size_t)s2 * DIM + q * 4);
        const float4 v3 = *reinterpret_cast<const float4*>(h + (size_t)s3 * DIM + q * 4);
        a0.x += v0.x + v1.x; a0.y += v0.y + v1.y; a0.z += v0.z + v1.z; a0.w += v0.w + v1.w;
        a1.x += v2.x + v3.x; a1.y += v2.y + v3.y; a1.z += v2.z + v3.z; a1.w += v2.w + v3.w;
    }
    for (; i < end; ++i) {
        int s = csr_src[i];
        const float4 v = *reinterpret_cast<const float4*>(h + (size_t)s * DIM + q * 4);
        a0.x += v.x; a0.y += v.y; a0.z += v.z; a0.w += v.w;
    }
    a0.x += a1.x; a0.y += a1.y; a0.z += a1.z; a0.w += a1.w;
    *reinterpret_cast<float4*>(&sAg[ln][q * 4]) = a0;
    __syncthreads();

    // dense combine: 16*48 = 768 jobs over 192 threads -> 4 iters
#pragma unroll
    for (int it = 0; it < 4; ++it) {
        unsigned idx = it * THREADS + threadIdx.x;
        unsigned l2 = idx / DIM;   // 0..15
        unsigned j  = idx % DIM;   // 0..47
        float a = sbr[j];
#pragma unroll
        for (int k = 0; k < DIM; ++k) {
            a += sAg[l2][k] * sWr[k * DIM + j];
            a += sH[l2][k] * sWk[k * DIM + j];
        }
        out[(size_t)(blockIdx.x * NPB + l2) * DIM + j] = a;
    }
}

// ============ MLP head: sigmoid(relu(h@W0+b0)@W1+b1), 16 nodes/block ============
#define MLP_NPB 16
__global__ __launch_bounds__(128) void mlp_head(
    const float* __restrict__ h, const float* __restrict__ W0,
    const float* __restrict__ b0, const float* __restrict__ W1,
    const float* __restrict__ b1, float* __restrict__ out)
{
    __shared__ float sW0[DIM * 128];       // 24.6 KB
    __shared__ float sW1[128];
    __shared__ float sH[MLP_NPB][DIM];     // 3 KB
    __shared__ float red[2][MLP_NPB];
    const int t = threadIdx.x;             // 0..127

    // stage W0 via float4 (1536 float4 over 128 threads = 12 each)
    {
        const float4* W04 = reinterpret_cast<const float4*>(W0);
        float4* s4 = reinterpret_cast<float4*>(sW0);
#pragma unroll
        for (int i = 0; i < DIM * 128 / 4 / 128; ++i)
            s4[i * 128 + t] = W04[i * 128 + t];
    }
    sW1[t] = W1[t];
    // stage 16 h rows (192 float4 over 128 threads)
    {
        const float4* H4 = reinterpret_cast<const float4*>(h + (size_t)blockIdx.x * MLP_NPB * DIM);
        float4* s4 = reinterpret_cast<float4*>(&sH[0][0]);
        for (int i = t; i < MLP_NPB * DIM / 4; i += 128) s4[i] = H4[i];
    }
    __syncthreads();

    // thread t = hidden unit j; k-outer loop reuses W0[k][j] across 16 nodes
    float acc[MLP_NPB];
    const float b0j = b0[t];
#pragma unroll
    for (int m = 0; m < MLP_NPB; ++m) acc[m] = b0j;
#pragma unroll
    for (int k = 0; k < DIM; ++k) {
        const float w = sW0[k * 128 + t];
#pragma unroll
        for (int m = 0; m < MLP_NPB; ++m) acc[m] += sH[m][k] * w;
    }
    const float w1j = sW1[t];
    // per-node reduction over the 128 hidden units
#pragma unroll
    for (int m = 0; m < MLP_NPB; ++m) {
        float r = fmaxf(acc[m], 0.0f) * w1j;
        r += __shfl_xor(r, 32); r += __shfl_xor(r, 16); r += __shfl_xor(r, 8);
        r += __shfl_xor(r, 4);  r += __shfl_xor(r, 2);  r += __shfl_xor(r, 1);
        if ((t & 63) == 0) red[t >> 6][m] = r;
    }
    __syncthreads();
    if (t < MLP_NPB) {
        float s = red[0][t] + red[1][t] + b1[0];
        out[blockIdx.x * MLP_NPB + t] = 1.0f / (1.0f + expf(-s));
    }
}

extern "C" void kernel_launch(void* const* d_in, const int* in_sizes, int n_in,
                              void* d_out, int out_size, void* d_ws, size_t ws_size,
                              hipStream_t stream)
{
    const float* x     = (const float*)d_in[0];
    const int*   ei    = (const int*)d_in[1];
    const float* c0_Wr = (const float*)d_in[2];
    const float* c0_br = (const float*)d_in[3];
    const float* c0_Wk = (const float*)d_in[4];
    const float* c1_Wr = (const float*)d_in[5];
    const float* c1_br = (const float*)d_in[6];
    const float* c1_Wk = (const float*)d_in[7];
    const float* c2_Wr = (const float*)d_in[8];
    const float* c2_br = (const float*)d_in[9];
    const float* c2_Wk = (const float*)d_in[10];
    const float* m0_W  = (const float*)d_in[11];
    const float* m0_b  = (const float*)d_in[12];
    const float* m1_W  = (const float*)d_in[13];
    const float* m1_b  = (const float*)d_in[14];
    float* out = (float*)d_out;

    const int* src = ei;
    const int* dst = ei + N_EDGES;

    const size_t feat_elems = (size_t)N_NODES * DIM;
    char* w = (char*)d_ws;
    float* hA      = (float*)w;                   w += feat_elems * 4;       // 19.2 MB
    float* hB      = (float*)w;                   w += feat_elems * 4;       // 19.2 MB
    int*   deg     = (int*)w;                     w += N_NODES * 4;
    int*   cursor  = (int*)w;                     w += N_NODES * 4;
    int*   row_off = (int*)w;                     w += (N_NODES + 1) * 4;
    int*   bsum    = (int*)w;                     w += 512 * 4;
    int*   bsum_ex = (int*)w;                     w += 512 * 4;
    int*   csr_src = (int*)w;                     w += (size_t)N_EDGES * 4;  // 6.4 MB

    // ---- CSR build (once; reused by all 3 layers) ----
    hipMemsetAsync(deg, 0, N_NODES * sizeof(int), stream);
    hist_deg_xcd<<<FILL_GRID, 256, 0, stream>>>(dst, deg);
    block_sums<<<NODE_BLOCKS, 256, 0, stream>>>(deg, bsum);
    scan_block_sums<<<1, 512, 0, stream>>>(bsum, bsum_ex);
    write_offsets<<<NODE_BLOCKS, 256, 0, stream>>>(deg, bsum_ex, row_off, cursor);
    fill_csr_xcd<<<FILL_GRID, 256, 0, stream>>>(src, dst, cursor, csr_src);

    const int fusedGrid = N_NODES / NPB;  // 6250, exact

    // ---- layer 0: x -> hA ----
    fused_layer<<<fusedGrid, THREADS, 0, stream>>>(x, row_off, csr_src, c0_Wr, c0_br, c0_Wk, hA);
    // ---- layer 1: hA -> hB ----
    fused_layer<<<fusedGrid, THREADS, 0, stream>>>(hA, row_off, csr_src, c1_Wr, c1_br, c1_Wk, hB);
    // ---- layer 2: hB -> hA ----
    fused_layer<<<fusedGrid, THREADS, 0, stream>>>(hB, row_off, csr_src, c2_Wr, c2_br, c2_Wk, hA);

    // ---- MLP head ----
    mlp_head<<<N_NODES / MLP_NPB, 128, 0, stream>>>(hA, m0_W, m0_b, m1_W, m1_b, out);
}

// Round 14
// 535.405 us; speedup vs baseline: 1.6953x; 1.6953x over previous
//
#include <hip/hip_runtime.h>
#include <math.h>

#define N_NODES 100000
#define N_EDGES 1600000
#define DIM 48
#define NPB 16          // nodes per block (fused layer)
#define THREADS 192     // 16 nodes x 12 lanes
#define NODE_BLOCKS ((N_NODES + 255) / 256)   // 391
#define NXCD 8
#define XCD_RANGE (N_NODES / NXCD)            // 12500 exact
#define FILL_GRID 1024                        // multiple of 8
#define FILL_NGRP (FILL_GRID / NXCD)          // 128

// ============ CSR build (XCD-partitioned: each line written by one XCD) ============
__global__ __launch_bounds__(256) void hist_deg_xcd(
    const int* __restrict__ dst, int* __restrict__ deg)
{
    const int xcd = blockIdx.x & (NXCD - 1);      // heuristic: blockIdx%8 -> XCD
    const int grp = blockIdx.x >> 3;              // 0..FILL_NGRP-1
    const int lo = xcd * XCD_RANGE;
    const int hi = lo + XCD_RANGE;
    for (int e = grp * 256 + threadIdx.x; e < N_EDGES; e += FILL_NGRP * 256) {
        int d = dst[e];                            // coalesced
        if (d >= lo && d < hi) atomicAdd(&deg[d], 1);
    }
}

__global__ __launch_bounds__(256) void fill_csr_xcd(
    const int* __restrict__ src, const int* __restrict__ dst,
    int* __restrict__ cursor, int* __restrict__ csr_src)
{
    const int xcd = blockIdx.x & (NXCD - 1);
    const int grp = blockIdx.x >> 3;
    const int lo = xcd * XCD_RANGE;
    const int hi = lo + XCD_RANGE;
    for (int e = grp * 256 + threadIdx.x; e < N_EDGES; e += FILL_NGRP * 256) {
        int d = dst[e];                            // coalesced
        int s = src[e];                            // coalesced (load always)
        if (d >= lo && d < hi) {
            int pos = atomicAdd(&cursor[d], 1);
            csr_src[pos] = s;                      // pos within this XCD's csr range
        }
    }
}

__global__ __launch_bounds__(256) void block_sums(
    const int* __restrict__ deg, int* __restrict__ bsum)
{
    __shared__ int r[256];
    unsigned t = threadIdx.x;
    unsigned i = blockIdx.x * 256u + t;
    r[t] = (i < N_NODES) ? deg[i] : 0;
    __syncthreads();
    for (int s = 128; s > 0; s >>= 1) {
        if (t < (unsigned)s) r[t] += r[t + s];
        __syncthreads();
    }
    if (t == 0) bsum[blockIdx.x] = r[0];
}

// single block, 512 threads: exclusive scan of bsum[0..NODE_BLOCKS)
__global__ __launch_bounds__(512) void scan_block_sums(
    const int* __restrict__ bsum, int* __restrict__ bsum_ex)
{
    __shared__ int s[512];
    unsigned t = threadIdx.x;
    int v = (t < NODE_BLOCKS) ? bsum[t] : 0;
    s[t] = v;
    __syncthreads();
    for (int off = 1; off < 512; off <<= 1) {
        int u = (t >= (unsigned)off) ? s[t - off] : 0;
        __syncthreads();
        s[t] += u;
        __syncthreads();
    }
    bsum_ex[t] = s[t] - v;   // exclusive
}

__global__ __launch_bounds__(256) void write_offsets(
    const int* __restrict__ deg, const int* __restrict__ bsum_ex,
    int* __restrict__ row_off, int* __restrict__ cursor)
{
    __shared__ int s[256];
    unsigned t = threadIdx.x;
    unsigned i = blockIdx.x * 256u + t;
    int v = (i < N_NODES) ? deg[i] : 0;
    s[t] = v;
    __syncthreads();
    for (int off = 1; off < 256; off <<= 1) {
        int u = (t >= (unsigned)off) ? s[t - off] : 0;
        __syncthreads();
        s[t] += u;
        __syncthreads();
    }
    if (i < N_NODES) {
        int o = bsum_ex[blockIdx.x] + s[t] - v;  // exclusive prefix
        row_off[i] = o;
        cursor[i] = o;
    }
    if (i == 0) row_off[N_NODES] = N_EDGES;
}

// ============ fused layer: out = (CSR-gather-sum of h) @ Wr + br + h @ Wk ============
// 192 threads = 16 nodes x 12 lanes. Phase 1: gather to LDS. Phase 2: dense combine.
__global__ __launch_bounds__(THREADS) void fused_layer(
    const float* __restrict__ h, const int* __restrict__ row_off,
    const int* __restrict__ csr_src,
    const float* __restrict__ Wr, const float* __restrict__ br,
    const float* __restrict__ Wk, float* __restrict__ out)
{
    __shared__ float sWr[DIM * DIM];
    __shared__ float sWk[DIM * DIM];
    __shared__ float sbr[DIM];
    __shared__ float sAg[NPB][DIM];
    __shared__ float sH[NPB][DIM];

    // stage weights (once per block)
    for (int i = threadIdx.x; i < DIM * DIM; i += THREADS) {
        sWr[i] = Wr[i];
        sWk[i] = Wk[i];
    }
    if (threadIdx.x < DIM) sbr[threadIdx.x] = br[threadIdx.x];

    const unsigned ln = threadIdx.x / 12u;   // 0..15
    const unsigned q  = threadIdx.x % 12u;   // 0..11
    const unsigned node = blockIdx.x * NPB + ln;  // grid exact: 6250*16 = 100000

    // stage own h row
    const float4 hv = *reinterpret_cast<const float4*>(h + (size_t)node * DIM + q * 4);
    *reinterpret_cast<float4*>(&sH[ln][q * 4]) = hv;

    // CSR gather-sum, unrolled x4 for memory-level parallelism
    const int beg = row_off[node];
    const int end = row_off[node + 1];
    float4 a0 = make_float4(0.f, 0.f, 0.f, 0.f);
    float4 a1 = make_float4(0.f, 0.f, 0.f, 0.f);
    int i = beg;
    for (; i + 4 <= end; i += 4) {
        int s0 = csr_src[i + 0];
        int s1 = csr_src[i + 1];
        int s2 = csr_src[i + 2];
        int s3 = csr_src[i + 3];
        const float4 v0 = *reinterpret_cast<const float4*>(h + (size_t)s0 * DIM + q * 4);
        const float4 v1 = *reinterpret_cast<const float4*>(h + (size_t)s1 * DIM + q * 4);
        const float4 v2 = *reinterpret_cast<const float4*>(h + (size_t)s2 * DIM + q * 4);
        const float4 v3 = *reinterpret_cast<const float4*>(h + (size_t)s3 * DIM + q * 4);
        a0.x += v0.x + v1.x; a0.y += v0.y + v1.y; a0.z += v0.z + v1.z; a0.w += v0.w + v1.w;
        a1.x += v2.x + v3.x; a1.y += v2.y + v3.y; a1.z += v2.z + v3.z; a1.w += v2.w + v3.w;
    }
    for (; i < end; ++i) {
        int s = csr_src[i];
        const float4 v = *reinterpret_cast<const float4*>(h + (size_t)s * DIM + q * 4);
        a0.x += v.x; a0.y += v.y; a0.z += v.z; a0.w += v.w;
    }
    a0.x += a1.x; a0.y += a1.y; a0.z += a1.z; a0.w += a1.w;
    *reinterpret_cast<float4*>(&sAg[ln][q * 4]) = a0;
    __syncthreads();

    // dense combine: 16*48 = 768 jobs over 192 threads -> 4 iters
#pragma unroll
    for (int it = 0; it < 4; ++it) {
        unsigned idx = it * THREADS + threadIdx.x;
        unsigned l2 = idx / DIM;   // 0..15
        unsigned j  = idx % DIM;   // 0..47
        float a = sbr[j];
#pragma unroll
        for (int k = 0; k < DIM; ++k) {
            a += sAg[l2][k] * sWr[k * DIM + j];
            a += sH[l2][k] * sWk[k * DIM + j];
        }
        out[(size_t)(blockIdx.x * NPB + l2) * DIM + j] = a;
    }
}

// ============ MLP head: sigmoid(relu(h@W0+b0)@W1+b1), 16 nodes/block ============
// v2: transposed sHT[k][m] tile (float4 broadcast reads), k-loop unroll capped at 2,
// __launch_bounds__(128,4) caps VGPR<=128. Fixes the 256-VGPR spill (434us, 1.3GB scratch).
#define MLP_NPB 16
__global__ __launch_bounds__(128, 4) void mlp_head(
    const float* __restrict__ h, const float* __restrict__ W0,
    const float* __restrict__ b0, const float* __restrict__ W1,
    const float* __restrict__ b1, float* __restrict__ out)
{
    __shared__ float sW0[DIM * 128];       // 24.6 KB
    __shared__ float sW1[128];
    __shared__ float sHT[DIM][MLP_NPB];    // transposed: [k][m], 3 KB
    __shared__ float red[2][MLP_NPB];
    const int t = threadIdx.x;             // 0..127

    // stage W0 via float4 (1536 float4 over 128 threads = 12 each)
    {
        const float4* W04 = reinterpret_cast<const float4*>(W0);
        float4* s4 = reinterpret_cast<float4*>(sW0);
#pragma unroll
        for (int i = 0; i < DIM * 128 / 4 / 128; ++i)
            s4[i * 128 + t] = W04[i * 128 + t];
    }
    sW1[t] = W1[t];
    // stage 16 h rows transposed: 768 elems over 128 threads = 6 each
    {
        const float* H = h + (size_t)blockIdx.x * MLP_NPB * DIM;
        for (int i = t; i < MLP_NPB * DIM; i += 128) {
            int m = i / DIM;
            int k = i % DIM;
            sHT[k][m] = H[i];   // coalesced read; scattered LDS write (cheap)
        }
    }
    __syncthreads();

    // thread t = hidden unit j; k-loop (unroll 2) reuses W0[k][j] across 16 nodes
    float acc[MLP_NPB];
    const float b0j = b0[t];
#pragma unroll
    for (int m = 0; m < MLP_NPB; ++m) acc[m] = b0j;
#pragma unroll 2
    for (int k = 0; k < DIM; ++k) {
        const float w = sW0[k * 128 + t];
        const float4 h0 = *reinterpret_cast<const float4*>(&sHT[k][0]);
        const float4 h1 = *reinterpret_cast<const float4*>(&sHT[k][4]);
        const float4 h2 = *reinterpret_cast<const float4*>(&sHT[k][8]);
        const float4 h3 = *reinterpret_cast<const float4*>(&sHT[k][12]);
        acc[0]  += h0.x * w; acc[1]  += h0.y * w; acc[2]  += h0.z * w; acc[3]  += h0.w * w;
        acc[4]  += h1.x * w; acc[5]  += h1.y * w; acc[6]  += h1.z * w; acc[7]  += h1.w * w;
        acc[8]  += h2.x * w; acc[9]  += h2.y * w; acc[10] += h2.z * w; acc[11] += h2.w * w;
        acc[12] += h3.x * w; acc[13] += h3.y * w; acc[14] += h3.z * w; acc[15] += h3.w * w;
    }
    const float w1j = sW1[t];
    // per-node reduction over the 128 hidden units
#pragma unroll
    for (int m = 0; m < MLP_NPB; ++m) {
        float r = fmaxf(acc[m], 0.0f) * w1j;
        r += __shfl_xor(r, 32); r += __shfl_xor(r, 16); r += __shfl_xor(r, 8);
        r += __shfl_xor(r, 4);  r += __shfl_xor(r, 2);  r += __shfl_xor(r, 1);
        if ((t & 63) == 0) red[t >> 6][m] = r;
    }
    __syncthreads();
    if (t < MLP_NPB) {
        float s = red[0][t] + red[1][t] + b1[0];
        out[blockIdx.x * MLP_NPB + t] = 1.0f / (1.0f + expf(-s));
    }
}

extern "C" void kernel_launch(void* const* d_in, const int* in_sizes, int n_in,
                              void* d_out, int out_size, void* d_ws, size_t ws_size,
                              hipStream_t stream)
{
    const float* x     = (const float*)d_in[0];
    const int*   ei    = (const int*)d_in[1];
    const float* c0_Wr = (const float*)d_in[2];
    const float* c0_br = (const float*)d_in[3];
    const float* c0_Wk = (const float*)d_in[4];
    const float* c1_Wr = (const float*)d_in[5];
    const float* c1_br = (const float*)d_in[6];
    const float* c1_Wk = (const float*)d_in[7];
    const float* c2_Wr = (const float*)d_in[8];
    const float* c2_br = (const float*)d_in[9];
    const float* c2_Wk = (const float*)d_in[10];
    const float* m0_W  = (const float*)d_in[11];
    const float* m0_b  = (const float*)d_in[12];
    const float* m1_W  = (const float*)d_in[13];
    const float* m1_b  = (const float*)d_in[14];
    float* out = (float*)d_out;

    const int* src = ei;
    const int* dst = ei + N_EDGES;

    const size_t feat_elems = (size_t)N_NODES * DIM;
    char* w = (char*)d_ws;
    float* hA      = (float*)w;                   w += feat_elems * 4;       // 19.2 MB
    float* hB      = (float*)w;                   w += feat_elems * 4;       // 19.2 MB
    int*   deg     = (int*)w;                     w += N_NODES * 4;
    int*   cursor  = (int*)w;                     w += N_NODES * 4;
    int*   row_off = (int*)w;                     w += (N_NODES + 1) * 4;
    int*   bsum    = (int*)w;                     w += 512 * 4;
    int*   bsum_ex = (int*)w;                     w += 512 * 4;
    int*   csr_src = (int*)w;                     w += (size_t)N_EDGES * 4;  // 6.4 MB

    // ---- CSR build (once; reused by all 3 layers) ----
    hipMemsetAsync(deg, 0, N_NODES * sizeof(int), stream);
    hist_deg_xcd<<<FILL_GRID, 256, 0, stream>>>(dst, deg);
    block_sums<<<NODE_BLOCKS, 256, 0, stream>>>(deg, bsum);
    scan_block_sums<<<1, 512, 0, stream>>>(bsum, bsum_ex);
    write_offsets<<<NODE_BLOCKS, 256, 0, stream>>>(deg, bsum_ex, row_off, cursor);
    fill_csr_xcd<<<FILL_GRID, 256, 0, stream>>>(src, dst, cursor, csr_src);

    const int fusedGrid = N_NODES / NPB;  // 6250, exact

    // ---- layer 0: x -> hA ----
    fused_layer<<<fusedGrid, THREADS, 0, stream>>>(x, row_off, csr_src, c0_Wr, c0_br, c0_Wk, hA);
    // ---- layer 1: hA -> hB ----
    fused_layer<<<fusedGrid, THREADS, 0, stream>>>(hA, row_off, csr_src, c1_Wr, c1_br, c1_Wk, hB);
    // ---- layer 2: hB -> hA ----
    fused_layer<<<fusedGrid, THREADS, 0, stream>>>(hB, row_off, csr_src, c2_Wr, c2_br, c2_Wk, hA);

    // ---- MLP head ----
    mlp_head<<<N_NODES / MLP_NPB, 128, 0, stream>>>(hA, m0_W, m0_b, m1_W, m1_b, out);
}